// Round 4
// baseline (216.743 us; speedup 1.0000x reference)
//
#include <hip/hip_runtime.h>
#include <math.h>

#define BB 8
#define NN 512
#define FF 128
#define TT 32
#define DD 64
constexpr float EPS = 1e-6f;

typedef _Float16 half8 __attribute__((ext_vector_type(8)));
typedef _Float16 half4v __attribute__((ext_vector_type(4)));
typedef float f32x4 __attribute__((ext_vector_type(4)));

__device__ __forceinline__ float fast_tanh(float v) {
    float e = __expf(2.f * v);
    return 1.f - 2.f * __builtin_amdgcn_rcpf(e + 1.f);
}

// ---------------- Stage 1: z = tanh(x @ W^T + b) -> fp16 hi/lo split in k-octet-major layout ----------------
// z layout: [b][t][ko][n][8] where ko = d>>3
// grid: B * (N/2) = 2048 blocks, 256 threads
__global__ __launch_bounds__(256) void z_kernel(const float* __restrict__ x,
                                                const float* __restrict__ W,
                                                const float* __restrict__ bias,
                                                _Float16* __restrict__ zh,
                                                _Float16* __restrict__ zl,
                                                float* __restrict__ sqv,
                                                float* __restrict__ nvv) {
    extern __shared__ float lds[];
    float* xs = lds;                      // 2*32*132 floats
    float* Wt = lds + 2 * 32 * 132;       // 128*64 floats
    const int tid = threadIdx.x;
    const int b  = blockIdx.x >> 8;
    const int n0 = (blockIdx.x & 255) * 2;

    const float4* W4 = (const float4*)W;
    #pragma unroll
    for (int it = 0; it < 8; ++it) {
        int idx4 = tid + it * 256;
        float4 w = W4[idx4];
        int d = idx4 >> 5;
        int f = (idx4 & 31) * 4;
        Wt[(f + 0) * 64 + d] = w.x;
        Wt[(f + 1) * 64 + d] = w.y;
        Wt[(f + 2) * 64 + d] = w.z;
        Wt[(f + 3) * 64 + d] = w.w;
    }
    const float4* x4 = (const float4*)(x + ((size_t)b * NN + n0) * FF * TT);
    #pragma unroll
    for (int it = 0; it < 8; ++it) {
        int idx4 = tid + it * 256;
        float4 v = x4[idx4];
        int e   = idx4 * 4;
        int ns  = e >> 12;
        int rem = e & 4095;
        int f   = rem >> 5;
        int t   = rem & 31;
        float* base = xs + ns * (32 * 132) + t * 132 + f;
        base[0 * 132] = v.x;
        base[1 * 132] = v.y;
        base[2 * 132] = v.z;
        base[3 * 132] = v.w;
    }
    __syncthreads();

    const int t  = tid >> 3;
    const int dg = tid & 7;
    const int d0 = dg * 8;
    float acc[2][8];
    #pragma unroll
    for (int ns = 0; ns < 2; ++ns)
        #pragma unroll
        for (int dd = 0; dd < 8; ++dd) acc[ns][dd] = 0.f;

    #pragma unroll 4
    for (int fc = 0; fc < FF; fc += 4) {
        float wv[4][8];
        #pragma unroll
        for (int k = 0; k < 4; ++k) {
            float4 a = *(const float4*)&Wt[(fc + k) * 64 + d0];
            float4 c = *(const float4*)&Wt[(fc + k) * 64 + d0 + 4];
            wv[k][0] = a.x; wv[k][1] = a.y; wv[k][2] = a.z; wv[k][3] = a.w;
            wv[k][4] = c.x; wv[k][5] = c.y; wv[k][6] = c.z; wv[k][7] = c.w;
        }
        #pragma unroll
        for (int ns = 0; ns < 2; ++ns) {
            float4 xv = *(const float4*)&xs[ns * (32 * 132) + t * 132 + fc];
            float xk[4] = {xv.x, xv.y, xv.z, xv.w};
            #pragma unroll
            for (int dd = 0; dd < 8; ++dd) {
                acc[ns][dd] += xk[0] * wv[0][dd] + xk[1] * wv[1][dd]
                             + xk[2] * wv[2][dd] + xk[3] * wv[3][dd];
            }
        }
    }

    float bb[8];
    #pragma unroll
    for (int dd = 0; dd < 8; ++dd) bb[dd] = bias[d0 + dd];

    const size_t planebase = ((size_t)b * TT + t) * NN * DD;
    const size_t rowbase   = ((size_t)b * TT + t) * NN + n0;
    float sqp[2];
    #pragma unroll
    for (int ns = 0; ns < 2; ++ns) {
        half8 hv, lv;
        float sp = 0.f;
        #pragma unroll
        for (int dd = 0; dd < 8; ++dd) {
            float zf = fast_tanh(acc[ns][dd] + bb[dd]);
            sp += zf * zf;
            _Float16 h = (_Float16)zf;
            hv[dd] = h;
            lv[dd] = (_Float16)(zf - (float)h);
        }
        size_t off = planebase + ((size_t)dg * NN + (n0 + ns)) * 8;
        *(half8*)(zh + off) = hv;
        *(half8*)(zl + off) = lv;
        sqp[ns] = sp;
    }
    #pragma unroll
    for (int k = 1; k < 8; k <<= 1) {
        #pragma unroll
        for (int ns = 0; ns < 2; ++ns) sqp[ns] += __shfl_xor(sqp[ns], k);
    }
    if (dg == 0) {
        #pragma unroll
        for (int ns = 0; ns < 2; ++ns) {
            sqv[rowbase + ns] = sqp[ns];
            nvv[rowbase + ns] = sqrtf(sqp[ns]) + EPS;
        }
    }
}

// ---------------- Stage 2: S = Z Z^T via split-fp16 MFMA ----------------
// grid: 512 blocks (t = bid&31, rowgroup32 = bid>>5), 512 threads = 8 waves.
// wave w: rowtile rt = w>>2 (16 rows at n0+rt*16), colgroup cg = w&3 (128 cols at cg*128, 8 ct tiles).
__global__ __launch_bounds__(512, 4) void att4_kernel(const _Float16* __restrict__ zh,
                                                      const _Float16* __restrict__ zl,
                                                      const float* __restrict__ sqv,
                                                      const float* __restrict__ nvv,
                                                      float* __restrict__ out) {
    __shared__ float nv_s[BB][NN];
    __shared__ float sq_s[BB][NN];
    __shared__ float rs_s[2][2][4][16];
    const int tid  = threadIdx.x;
    const int w    = tid >> 6;
    const int lane = tid & 63;
    const int l15  = lane & 15;
    const int g    = lane >> 4;
    const int rt   = w >> 2;
    const int cg   = w & 3;
    const int t    = blockIdx.x & 31;
    const int n0   = (blockIdx.x >> 5) * 32;

    // stage all-b norms once (one barrier total for staging)
    #pragma unroll
    for (int b8 = 0; b8 < BB; ++b8) {
        const size_t nbase = ((size_t)b8 * TT + t) * NN;
        nv_s[b8][tid] = nvv[nbase + tid];
        sq_s[b8][tid] = sqv[nbase + tid];
    }
    __syncthreads();

    float acc[8][4];
    #pragma unroll
    for (int ct = 0; ct < 8; ++ct)
        #pragma unroll
        for (int ri = 0; ri < 4; ++ri) acc[ct][ri] = 0.f;

    half4v atth[8];

    for (int b = 0; b < BB; ++b) {
        const int p = b & 1;
        const size_t slab = ((size_t)b * TT + t) * NN * DD;
        const _Float16* zhp = zh + slab;
        const _Float16* zlp = zl + slab;

        // A fragments: rows n0 + rt*16 + l15, plane ko = s*4+g
        half8 ah[2], al[2];
        #pragma unroll
        for (int s = 0; s < 2; ++s) {
            const size_t ro = ((size_t)(s * 4 + g) * NN + n0 + rt * 16 + l15) * 8;
            ah[s] = *(const half8*)(zhp + ro);
            al[s] = *(const half8*)(zlp + ro);
        }

        float nr[4], sq_r[4], nri[4];
        #pragma unroll
        for (int ri = 0; ri < 4; ++ri) {
            int row = n0 + rt * 16 + g * 4 + ri;
            nr[ri]   = nv_s[b][row];
            sq_r[ri] = sq_s[b][row];
            nri[ri]  = __builtin_amdgcn_rcpf(nr[ri]);
        }

        float rs[4] = {0.f, 0.f, 0.f, 0.f};

        #pragma unroll
        for (int ct = 0; ct < 8; ++ct) {
            const int col = cg * 128 + ct * 16 + l15;
            const size_t c0 = ((size_t)(0 * 4 + g) * NN + col) * 8;
            const size_t c1 = ((size_t)(1 * 4 + g) * NN + col) * 8;
            half8 bh0 = *(const half8*)(zhp + c0);
            half8 bh1 = *(const half8*)(zhp + c1);
            half8 bl0 = *(const half8*)(zlp + c0);
            half8 bl1 = *(const half8*)(zlp + c1);

            // 3 independent 2-deep MFMA chains
            f32x4 dhh = {0.f, 0.f, 0.f, 0.f};
            f32x4 dhl = {0.f, 0.f, 0.f, 0.f};
            f32x4 dlh = {0.f, 0.f, 0.f, 0.f};
            dhh = __builtin_amdgcn_mfma_f32_16x16x32_f16(ah[0], bh0, dhh, 0, 0, 0);
            dhl = __builtin_amdgcn_mfma_f32_16x16x32_f16(ah[0], bl0, dhl, 0, 0, 0);
            dlh = __builtin_amdgcn_mfma_f32_16x16x32_f16(al[0], bh0, dlh, 0, 0, 0);
            dhh = __builtin_amdgcn_mfma_f32_16x16x32_f16(ah[1], bh1, dhh, 0, 0, 0);
            dhl = __builtin_amdgcn_mfma_f32_16x16x32_f16(ah[1], bl1, dhl, 0, 0, 0);
            dlh = __builtin_amdgcn_mfma_f32_16x16x32_f16(al[1], bh1, dlh, 0, 0, 0);
            f32x4 d = dhh + dhl + dlh;

            const float nm  = nv_s[b][col];
            const float sqm = sq_s[b][col];
            const float nmi = __builtin_amdgcn_rcpf(nm);
            float pr[4], s2[4], rc[4];
            #pragma unroll
            for (int ri = 0; ri < 4; ++ri) {
                pr[ri] = nri[ri] * nmi;
                s2[ri] = sq_r[ri] + sqm;
                rc[ri] = __builtin_amdgcn_rcpf(nr[ri] + nm + EPS);
            }
            #pragma unroll
            for (int ri = 0; ri < 4; ++ri) {
                float dot = d[ri];
                float cs  = dot * pr[ri];
                float d2  = fmaxf(fmaf(dot, -2.f, s2[ri]), 0.f);
                float dn  = __builtin_amdgcn_sqrtf(d2);
                float a   = __expf(fmaf(dn, -rc[ri], cs));
                atth[ct][ri] = (_Float16)a;
                rs[ri] += a;
            }
        }

        // row-sum across the 16 lanes of each g-group (covers this wave's 128 cols)
        #pragma unroll
        for (int ri = 0; ri < 4; ++ri) {
            float v = rs[ri];
            v += __shfl_xor(v, 1);
            v += __shfl_xor(v, 2);
            v += __shfl_xor(v, 4);
            v += __shfl_xor(v, 8);
            rs[ri] = v;
        }
        if (l15 == 0) {
            #pragma unroll
            for (int ri = 0; ri < 4; ++ri)
                rs_s[p][rt][cg][g * 4 + ri] = rs[ri];
        }
        __syncthreads();
        #pragma unroll
        for (int ri = 0; ri < 4; ++ri) {
            int rl = g * 4 + ri;
            float tot = rs_s[p][rt][0][rl] + rs_s[p][rt][1][rl]
                      + rs_s[p][rt][2][rl] + rs_s[p][rt][3][rl];
            float rinv = __builtin_amdgcn_rcpf(tot + EPS);
            #pragma unroll
            for (int ct = 0; ct < 8; ++ct)
                acc[ct][ri] += (float)atth[ct][ri] * rinv;
        }
    }

    #pragma unroll
    for (int ri = 0; ri < 4; ++ri) {
        const size_t ob = ((size_t)t * NN + n0 + rt * 16 + g * 4 + ri) * NN + cg * 128 + l15;
        #pragma unroll
        for (int ct = 0; ct < 8; ++ct)
            out[ob + ct * 16] = acc[ct][ri] * 0.125f;
    }
}

extern "C" void kernel_launch(void* const* d_in, const int* in_sizes, int n_in,
                              void* d_out, int out_size, void* d_ws, size_t ws_size,
                              hipStream_t stream) {
    const float* x    = (const float*)d_in[0];
    const float* W    = (const float*)d_in[1];
    const float* bias = (const float*)d_in[2];
    float* out = (float*)d_out;

    const size_t ZELEMS = (size_t)BB * TT * NN * DD;
    _Float16* zh = (_Float16*)d_ws;
    _Float16* zl = zh + ZELEMS;
    float* sqv = (float*)(zh + 2 * ZELEMS);
    float* nvv = sqv + (size_t)BB * TT * NN;

    z_kernel<<<dim3(BB * (NN / 2)), dim3(256), 66560, stream>>>(x, W, bias, zh, zl, sqv, nvv);
    att4_kernel<<<dim3(TT * (NN / 32)), dim3(512), 0, stream>>>(zh, zl, sqv, nvv, out);
}